// Round 9
// baseline (1559.775 us; speedup 1.0000x reference)
//
#include <hip/hip_runtime.h>
#include <math.h>

typedef unsigned int uint;
typedef unsigned long long u64;

#define C_ 128
static const int N0 = 65536;
static const int E0 = 1048576;
static const int K0 = 32768, K1 = 16384, K2 = 8192;
static const int CAP1 = 524288, CAP2 = 262144, CAP3 = 131072;

__device__ inline float wave_reduce_sum(float v) {
#pragma unroll
  for (int w = 32; w >= 1; w >>= 1) v += __shfl_xor(v, w, 64);
  return v;
}

// per-row squared norm + score = sqrt(ss + 1e-12). One wave per row.
__global__ void score_kernel(const float* __restrict__ x, float* __restrict__ score,
                             float* __restrict__ ss) {
  int row = blockIdx.x * 4 + (threadIdx.x >> 6);
  int lane = threadIdx.x & 63;
  float2 v = ((const float2*)(x + (size_t)row * C_))[lane];
  float s = v.x * v.x + v.y * v.y;
  s = wave_reduce_sum(s);
  if (lane == 0) { ss[row] = s; score[row] = sqrtf(s + 1e-12f); }
}

// ---- grid-parallel top-k select: 2x16-bit radix over 65536-bin global hists
// (r8 post-mortem: single-block radix select ran 145us at 0.18% occupancy --
// one CU busy, 255 idle. These kernels spread the histogram over the grid.)

// histogram of top 16 bits of the float key (all keys positive).
__global__ void hist_hi_kernel(const float* __restrict__ score, int n,
                               int* __restrict__ hist) {
  int i = blockIdx.x * 256 + threadIdx.x;
  if (i < n) atomicAdd(&hist[((const uint*)score)[i] >> 16], 1);
}

// histogram of low 16 bits for keys matching the hi-prefix chosen so far.
__global__ void hist_lo_kernel(const float* __restrict__ score, int n,
                               const uint* __restrict__ kth_ptr, int* __restrict__ hist) {
  uint pre = *kth_ptr >> 16;
  int i = blockIdx.x * 256 + threadIdx.x;
  if (i < n) {
    uint key = ((const uint*)score)[i];
    if ((key >> 16) == pre) atomicAdd(&hist[key & 0xFFFFu], 1);
  }
}

// single-block: suffix-scan 65536 bins from the top, pick the bucket holding
// the kth-largest, fold it into *kth at `shift`, update *rem.
__global__ __launch_bounds__(1024) void radix_scan_kernel(const int* __restrict__ hist,
                                                          int k_init, int use_init,
                                                          uint* __restrict__ kth,
                                                          int* __restrict__ rem, int shift) {
  __shared__ int part[1024];
  __shared__ int chunkidx;
  int tid = threadIdx.x;
  int s = 0;
  int base = tid * 64;
  for (int j = 0; j < 64; ++j) s += hist[base + j];
  part[tid] = s;
  __syncthreads();
  // Hillis-Steele suffix scan: part[t] = sum_{t'>=t} chunk_sum[t']
  for (int d = 1; d < 1024; d <<= 1) {
    int add = (tid + d < 1024) ? part[tid + d] : 0;
    __syncthreads();
    part[tid] += add;
    __syncthreads();
  }
  int remv = use_init ? k_init : *rem;
  if (tid == 0) {
    int c = 1023;
    while (c >= 0 && part[c] < remv) --c;  // largest c with suffix >= rem
    chunkidx = c;
  }
  __syncthreads();
  if (tid == 0) {
    int c = chunkidx;
    int above = (c + 1 < 1024) ? part[c + 1] : 0;
    int b = c * 64 + 63;
    int acc = above;
    for (;; --b) { acc += hist[b]; if (acc >= remv) break; }
    *rem = remv - (acc - hist[b]);  // how many kth-equal keys to include
    *kth |= ((uint)b) << shift;
  }
}

// collect indices of keys exactly equal to kth (typically 0 or 1 beyond the one).
__global__ void tie_collect_kernel(const float* __restrict__ score, int n,
                                   const uint* __restrict__ kth_ptr,
                                   int* __restrict__ eqlist, int* __restrict__ eqn) {
  uint kth = *kth_ptr;
  int i = blockIdx.x * 256 + threadIdx.x;
  if (i < n && ((const uint*)score)[i] == kth) {
    int p = atomicAdd(eqn, 1);
    if (p < 4096) eqlist[p] = i;
  }
}

// mark the `rem` lowest-index ties with map = -2 (top_k stable tie-break).
__global__ void tie_mark_kernel(int* __restrict__ eqlist, const int* __restrict__ eqn_ptr,
                                const int* __restrict__ rem_ptr, int* __restrict__ map) {
  if (threadIdx.x != 0) return;
  int need = *rem_ptr;
  int tot = min(*eqn_ptr, 4096);
  for (int t = 0; t < need && t < tot; ++t) {
    int mi = -1, mv = 0x7FFFFFFF;
    for (int q = 0; q < tot; ++q) { int v = eqlist[q]; if (v >= 0 && v < mv) { mv = v; mi = q; } }
    if (mi < 0) break;
    map[mv] = -2;
    eqlist[mi] = -1;
  }
}

// compact selected nodes -> perm/map/gate (+ optional fused L_FP term).
// ONE counter atomic per block (r6: per-wave same-address atomics-with-return
// serialize ~29cyc each). Two-pass: count -> block scan -> one atomicAdd ->
// ballot-slot write. Grid must satisfy grid*1024 == n.
__global__ __launch_bounds__(256) void build_perm_kernel(
    const float* __restrict__ score, const float* __restrict__ ss,
    const uint* __restrict__ kth_ptr, int* __restrict__ map, int* __restrict__ perm,
    float* __restrict__ gate, int* __restrict__ ctr, float lfp_scale,
    float* __restrict__ Lacc) {
  const int ITER = 4;
  int tid = threadIdx.x, lane = tid & 63, wid = tid >> 6;
  __shared__ int wbase[4];
  __shared__ int gbase;
  __shared__ float pl[4];
  uint kth = *kth_ptr;
  int base = blockIdx.x * (256 * ITER);
  int cnt = 0;
#pragma unroll
  for (int l = 0; l < ITER; ++l) {
    int i = base + l * 256 + tid;
    uint key = ((const uint*)score)[i];
    if ((key > kth) || (map[i] == -2)) ++cnt;
  }
#pragma unroll
  for (int w = 32; w >= 1; w >>= 1) cnt += __shfl_xor(cnt, w, 64);
  if (lane == 0) wbase[wid] = cnt;
  __syncthreads();
  if (tid == 0) {
    int s = 0;
#pragma unroll
    for (int i = 0; i < 4; ++i) { int c = wbase[i]; wbase[i] = s; s += c; }
    gbase = s ? atomicAdd(ctr, s) : 0;
  }
  __syncthreads();
  int woff = gbase + wbase[wid];
  float lfp = 0.f;
#pragma unroll
  for (int l = 0; l < ITER; ++l) {
    int i = base + l * 256 + tid;
    uint key = ((const uint*)score)[i];
    bool sel = (key > kth) || (map[i] == -2);
    u64 m = __ballot(sel);
    if (sel) {
      int j = woff + (int)__popcll(m & ((1ull << lane) - 1ull));
      perm[j] = i;
      map[i] = j;
      float t = tanhf(score[i]);
      gate[j] = t;
      if (lfp_scale != 0.f) { float om = 1.f - t; lfp += om * om * ss[i] * lfp_scale; }
    }
    woff += (int)__popcll(m);
  }
  if (lfp_scale != 0.f) {
    lfp = wave_reduce_sum(lfp);
    if (lane == 0) pl[wid] = lfp;
    __syncthreads();
    if (tid == 0) atomicAdd(Lacc, pl[0] + pl[1] + pl[2] + pl[3]);
  }
}

// xp[j] = x[perm[j]] * gate[j]   (32 threads/row, float4)
__global__ void pool_gather_kernel(const float* __restrict__ xin, const int* __restrict__ perm,
                                   const float* __restrict__ gate, float* __restrict__ xp) {
  int t = blockIdx.x * 256 + threadIdx.x;
  int j = t >> 5, q = t & 31;
  int p = perm[j];
  float g = gate[j];
  float4 v = ((const float4*)(xin + (size_t)p * C_))[q];
  v.x *= g; v.y *= g; v.z *= g; v.w *= g;
  ((float4*)(xp + (size_t)j * C_))[q] = v;
}

// filter edges whose both endpoints survive; relabel; fused degree histogram.
// ONE output-counter atomic per 2048-edge block chunk.
__global__ __launch_bounds__(256) void edge_compact_kernel(
    const int* __restrict__ src, const int* __restrict__ dst,
    const int* __restrict__ cnt_ptr, int in_cap, const int* __restrict__ map,
    int* __restrict__ osrc, int* __restrict__ odst, int* __restrict__ octr, int cap,
    int* __restrict__ deg) {
  const int ITER = 8;
  int n = cnt_ptr ? min(*cnt_ptr, in_cap) : in_cap;
  int tid = threadIdx.x, lane = tid & 63, wid = tid >> 6;
  __shared__ int wbase[4];
  __shared__ int gbase;
  long long chunk = 256 * ITER;
  for (long long base = (long long)blockIdx.x * chunk; base < n;
       base += (long long)gridDim.x * chunk) {
    int cnt = 0;
#pragma unroll
    for (int l = 0; l < ITER; ++l) {
      long long e = base + l * 256 + tid;
      if (e < n) {
        int a = map[src[e]];
        int b = map[dst[e]];
        if (a >= 0 && b >= 0) ++cnt;
      }
    }
#pragma unroll
    for (int w = 32; w >= 1; w >>= 1) cnt += __shfl_xor(cnt, w, 64);
    __syncthreads();
    if (lane == 0) wbase[wid] = cnt;
    __syncthreads();
    if (tid == 0) {
      int s = 0;
#pragma unroll
      for (int i = 0; i < 4; ++i) { int c = wbase[i]; wbase[i] = s; s += c; }
      gbase = s ? atomicAdd(octr, s) : 0;
    }
    __syncthreads();
    int woff = gbase + wbase[wid];
#pragma unroll
    for (int l = 0; l < ITER; ++l) {
      long long e = base + l * 256 + tid;
      int a = -1, b = -1;
      bool keep = false;
      if (e < n) {
        a = map[src[e]];
        b = map[dst[e]];
        keep = (a >= 0 && b >= 0);
      }
      u64 m = __ballot(keep);
      if (keep) {
        int p = woff + (int)__popcll(m & ((1ull << lane) - 1ull));
        if (p < cap) {
          osrc[p] = a;
          odst[p] = b;
          atomicAdd(&deg[b], 1);
        }
      }
      woff += (int)__popcll(m);
    }
  }
}

__global__ void hist_kernel(const int* __restrict__ dst, int n, int* __restrict__ deg) {
  for (int e = blockIdx.x * 256 + threadIdx.x; e < n; e += gridDim.x * 256)
    atomicAdd(&deg[dst[e]], 1);
}

// exclusive scan of degrees -> rowptr; cursor doubles as deg-in / offset-out.
__global__ __launch_bounds__(1024) void scan_kernel(int* __restrict__ cursor,
                                                    int* __restrict__ rowptr, int n) {
  __shared__ int part[1024];
  int tid = threadIdx.x;
  int chunk = (n + 1023) >> 10;
  int beg = tid * chunk, end = min(beg + chunk, n);
  int s = 0;
  for (int i = beg; i < end; ++i) s += cursor[i];
  part[tid] = s;
  __syncthreads();
  for (int d = 1; d < 1024; d <<= 1) {
    int v = part[tid];
    if (tid >= d) v += part[tid - d];
    __syncthreads();
    part[tid] = v;
    __syncthreads();
  }
  int off = part[tid] - s;
  for (int i = beg; i < end; ++i) { int dv = cursor[i]; rowptr[i] = off; cursor[i] = off; off += dv; }
  if (tid == 1023) rowptr[n] = part[1023];
}

__global__ void scatter_kernel(const int* __restrict__ src, const int* __restrict__ dst,
                               const int* __restrict__ cnt_ptr, int cap,
                               int* __restrict__ cursor, int* __restrict__ csr) {
  int n = cnt_ptr ? min(*cnt_ptr, cap) : cap;
  for (int e = blockIdx.x * 256 + threadIdx.x; e < n; e += gridDim.x * 256) {
    int p = atomicAdd(&cursor[dst[e]], 1);
    csr[p] = src[e];
  }
}

// mean[node] = (sum over CSR row) / max(deg,1). 32 threads/node, float4.
// fmap mode: x row = x[fmap[s]] if selected, else 0 (virtual unpool).
__global__ void agg_kernel(const float* __restrict__ x, const int* __restrict__ rowptr,
                           const int* __restrict__ csr, const int* __restrict__ fmap,
                           float* __restrict__ mean, int n) {
  int t = blockIdx.x * 256 + threadIdx.x;
  int node = t >> 5, q = t & 31;
  if (node >= n) return;
  int beg = rowptr[node], end = rowptr[node + 1];
  float4 acc = make_float4(0.f, 0.f, 0.f, 0.f);
  if (fmap) {
    for (int p = beg; p < end; ++p) {
      int m = fmap[csr[p]];
      if (m < 0) continue;
      float4 v = ((const float4*)(x + (size_t)m * C_))[q];
      acc.x += v.x; acc.y += v.y; acc.z += v.z; acc.w += v.w;
    }
  } else {
    for (int p = beg; p < end; ++p) {
      int s = csr[p];
      float4 v = ((const float4*)(x + (size_t)s * C_))[q];
      acc.x += v.x; acc.y += v.y; acc.z += v.z; acc.w += v.w;
    }
  }
  float inv = 1.f / fmaxf((float)(end - beg), 1.f);
  acc.x *= inv; acc.y *= inv; acc.z *= inv; acc.w *= inv;
  ((float4*)(mean + (size_t)node * C_))[q] = acc;
}

// out[row] = mean[row] @ Wl + Xsrc[xrow] @ Wr + b (optional relu).
__global__ __launch_bounds__(256) void gemm_kernel(const float* __restrict__ Amean,
                                                   const float* __restrict__ Xsrc,
                                                   const int* __restrict__ xmask,
                                                   const float* __restrict__ Wl,
                                                   const float* __restrict__ Wr,
                                                   const float* __restrict__ bias,
                                                   float* __restrict__ out, int relu,
                                                   float* __restrict__ Lout,
                                                   const float* __restrict__ Lacc) {
  __shared__ alignas(16) float As[32][68];
  __shared__ alignas(16) float Ws[32][128];
  __shared__ int rm[64];
  int tid = threadIdx.x;
  int row0 = blockIdx.x * 64;
  if (tid < 64) rm[tid] = xmask ? xmask[row0 + tid] : (row0 + tid);
  if (Lout && blockIdx.x == 0 && tid == 0) Lout[0] = *Lacc;
  int trow = tid >> 4;
  int tcol = tid & 15;
  float acc[4][8];
#pragma unroll
  for (int i = 0; i < 4; ++i)
#pragma unroll
    for (int j = 0; j < 8; ++j) acc[i][j] = 0.f;
  __syncthreads();
  for (int phase = 0; phase < 2; ++phase) {
    const float* A = phase ? Xsrc : Amean;
    const float* W = phase ? Wr : Wl;
    for (int kc = 0; kc < 128; kc += 32) {
#pragma unroll
      for (int l = 0; l < 2; ++l) {
        int f = tid + l * 256;
        int r = f >> 3, c4 = (f & 7) << 2;
        int xr = phase ? rm[r] : (row0 + r);
        float4 v = make_float4(0.f, 0.f, 0.f, 0.f);
        if (xr >= 0) v = *(const float4*)(A + (size_t)xr * C_ + kc + c4);
        As[c4 + 0][r] = v.x; As[c4 + 1][r] = v.y; As[c4 + 2][r] = v.z; As[c4 + 3][r] = v.w;
      }
#pragma unroll
      for (int l = 0; l < 4; ++l) {
        int f = tid + l * 256;
        int kk = f >> 5, c4 = (f & 31) << 2;
        *(float4*)(&Ws[kk][c4]) = *(const float4*)(W + (size_t)(kc + kk) * C_ + c4);
      }
      __syncthreads();
#pragma unroll
      for (int kk = 0; kk < 32; ++kk) {
        float a[4], w[8];
#pragma unroll
        for (int i = 0; i < 4; ++i) a[i] = As[kk][trow * 4 + i];
#pragma unroll
        for (int j = 0; j < 8; ++j) w[j] = Ws[kk][tcol * 8 + j];
#pragma unroll
        for (int i = 0; i < 4; ++i)
#pragma unroll
          for (int j = 0; j < 8; ++j) acc[i][j] = fmaf(a[i], w[j], acc[i][j]);
      }
      __syncthreads();
    }
  }
#pragma unroll
  for (int i = 0; i < 4; ++i) {
    int r = row0 + trow * 4 + i;
#pragma unroll
    for (int j = 0; j < 8; ++j) {
      float v = acc[i][j] + bias[tcol * 8 + j];
      if (relu) v = fmaxf(v, 0.f);
      out[(size_t)r * C_ + tcol * 8 + j] = v;
    }
  }
}

// fused: L_similarity + L_regularization + next level's score/ss.
__global__ void lsim_score_kernel(const float* __restrict__ h, const float* __restrict__ x0,
                                  const float* __restrict__ xin, const int* __restrict__ perm,
                                  float scale, float* __restrict__ Lacc,
                                  float* __restrict__ score, float* __restrict__ ss) {
  int row = blockIdx.x * 4 + (threadIdx.x >> 6);
  int lane = threadIdx.x & 63;
  int p = perm[row];
  float2 hv = ((const float2*)(h + (size_t)row * C_))[lane];
  float2 a = ((const float2*)(x0 + (size_t)p * C_))[lane];
  float2 bv = (xin == x0) ? a : ((const float2*)(xin + (size_t)p * C_))[lane];
  float d1x = hv.x - a.x, d1y = hv.y - a.y;
  float l = d1x * d1x + d1y * d1y + fabsf(hv.x - bv.x) + fabsf(hv.y - bv.y);
  float s2 = hv.x * hv.x + hv.y * hv.y;
#pragma unroll
  for (int w = 32; w >= 1; w >>= 1) { l += __shfl_xor(l, w, 64); s2 += __shfl_xor(s2, w, 64); }
  __shared__ float pl[4];
  int wid = threadIdx.x >> 6;
  if (lane == 0) {
    pl[wid] = l;
    if (score) { ss[row] = s2; score[row] = sqrtf(s2 + 1e-12f); }
  }
  __syncthreads();
  if (threadIdx.x == 0) atomicAdd(Lacc, (pl[0] + pl[1] + pl[2] + pl[3]) * scale);
}

extern "C" void kernel_launch(void* const* d_in, const int* in_sizes, int n_in, void* d_out,
                              int out_size, void* d_ws, size_t ws_size, hipStream_t stream) {
  const float* x0 = (const float*)d_in[0];
  const int* ei = (const int*)d_in[1];
  const float* Wl = (const float*)d_in[2];
  const float* Wr = (const float*)d_in[3];
  const float* bias = (const float*)d_in[4];
  float* out = (float*)d_out;

  char* base = (char*)d_ws;
  size_t off = 0;
  auto alloc = [&](size_t bytes) -> char* {
    char* p = base + off;
    off = (off + bytes + 255) & ~(size_t)255;
    return p;
  };

  // ---- zeroed region (one memset) ----
  int* ctrl = (int*)alloc(1024 * 4);
  // ctrl ints: 0..2 edge ctr, 4..6 perm ctr, 8..10 kth, 12..14 rem,
  //            16 Lacc(float), 20..22 eqn
  int* cur0 = (int*)alloc((size_t)(N0 + 1) * 4);
  int* cur1 = (int*)alloc((size_t)(K0 + 1) * 4);
  int* cur2 = (int*)alloc((size_t)(K1 + 1) * 4);
  int* cur3 = (int*)alloc((size_t)(K2 + 1) * 4);
  int* hhi0 = (int*)alloc(65536 * 4);
  int* hlo0 = (int*)alloc(65536 * 4);
  int* hhi1 = (int*)alloc(65536 * 4);
  int* hlo1 = (int*)alloc(65536 * 4);
  int* hhi2 = (int*)alloc(65536 * 4);
  int* hlo2 = (int*)alloc(65536 * 4);
  size_t zero_bytes = (size_t)((base + off) - (char*)ctrl);
  // ---- 0xFF region (one memset) ----
  int* map0 = (int*)alloc((size_t)N0 * 4);
  int* map1 = (int*)alloc((size_t)K0 * 4);
  int* map2 = (int*)alloc((size_t)K1 * 4);
  size_t ff_bytes = (size_t)((base + off) - (char*)map0);
  // ---- uninitialized (fully written before read every call) ----
  int* eql0 = (int*)alloc(4096 * 4);
  int* eql1 = (int*)alloc(4096 * 4);
  int* eql2 = (int*)alloc(4096 * 4);
  float* score0 = (float*)alloc((size_t)N0 * 4);
  float* ss0 = (float*)alloc((size_t)N0 * 4);
  float* score1 = (float*)alloc((size_t)K0 * 4);
  float* ss1 = (float*)alloc((size_t)K0 * 4);
  float* score2 = (float*)alloc((size_t)K1 * 4);
  float* ss2 = (float*)alloc((size_t)K1 * 4);
  int* perm0 = (int*)alloc((size_t)K0 * 4);
  int* perm1 = (int*)alloc((size_t)K1 * 4);
  int* perm2 = (int*)alloc((size_t)K2 * 4);
  float* gate0 = (float*)alloc((size_t)K0 * 4);
  float* gate1 = (float*)alloc((size_t)K1 * 4);
  float* gate2 = (float*)alloc((size_t)K2 * 4);
  int* e1s = (int*)alloc((size_t)CAP1 * 4);
  int* e1d = (int*)alloc((size_t)CAP1 * 4);
  int* e2s = (int*)alloc((size_t)CAP2 * 4);
  int* e2d = (int*)alloc((size_t)CAP2 * 4);
  int* e3s = (int*)alloc((size_t)CAP3 * 4);
  int* e3d = (int*)alloc((size_t)CAP3 * 4);
  int* rowptr0 = (int*)alloc((size_t)(N0 + 1) * 4);
  int* rowptr1 = (int*)alloc((size_t)(K0 + 1) * 4);
  int* rowptr2 = (int*)alloc((size_t)(K1 + 1) * 4);
  int* rowptr3 = (int*)alloc((size_t)(K2 + 1) * 4);
  int* csr0 = (int*)alloc((size_t)E0 * 4);
  int* csr1 = (int*)alloc((size_t)CAP1 * 4);
  int* csr2 = (int*)alloc((size_t)CAP2 * 4);
  int* csr3 = (int*)alloc((size_t)CAP3 * 4);
  float* xp = (float*)alloc((size_t)K0 * C_ * 4);  // pooled input / hup2
  float* h0 = (float*)alloc((size_t)K0 * C_ * 4);  // down h0, later hup1
  float* h1 = (float*)alloc((size_t)K1 * C_ * 4);
  float* h2 = (float*)alloc((size_t)K2 * C_ * 4);
  float* mean = (float*)alloc((size_t)N0 * C_ * 4);

  uint* kth0 = (uint*)(ctrl + 8);
  uint* kth1 = (uint*)(ctrl + 9);
  uint* kth2 = (uint*)(ctrl + 10);
  int* rem0 = ctrl + 12;
  int* rem1 = ctrl + 13;
  int* rem2 = ctrl + 14;
  float* Lacc = (float*)(ctrl + 16);
  int* eqn0 = ctrl + 20;
  int* eqn1 = ctrl + 21;
  int* eqn2 = ctrl + 22;
  const float sc0 = 1.f / ((float)K0 * C_);
  const float sc1 = 1.f / ((float)K1 * C_);
  const float sc2 = 1.f / ((float)K2 * C_);

  hipMemsetAsync(ctrl, 0, zero_bytes, stream);
  hipMemsetAsync(map0, 0xFF, ff_bytes, stream);

  // CSR over original edges (for the final conv)
  hist_kernel<<<2048, 256, 0, stream>>>(ei + E0, E0, cur0);
  scan_kernel<<<1, 1024, 0, stream>>>(cur0, rowptr0, N0);
  scatter_kernel<<<2048, 256, 0, stream>>>(ei, ei + E0, nullptr, E0, cur0, csr0);

  // ---------------- down level 0 ----------------
  score_kernel<<<N0 / 4, 256, 0, stream>>>(x0, score0, ss0);
  hist_hi_kernel<<<N0 / 256, 256, 0, stream>>>(score0, N0, hhi0);
  radix_scan_kernel<<<1, 1024, 0, stream>>>(hhi0, K0, 1, kth0, rem0, 16);
  hist_lo_kernel<<<N0 / 256, 256, 0, stream>>>(score0, N0, kth0, hlo0);
  radix_scan_kernel<<<1, 1024, 0, stream>>>(hlo0, 0, 0, kth0, rem0, 0);
  tie_collect_kernel<<<N0 / 256, 256, 0, stream>>>(score0, N0, kth0, eql0, eqn0);
  tie_mark_kernel<<<1, 64, 0, stream>>>(eql0, eqn0, rem0, map0);
  build_perm_kernel<<<N0 / 1024, 256, 0, stream>>>(score0, ss0, kth0, map0, perm0, gate0,
                                                   ctrl + 4, 0.f, Lacc);
  pool_gather_kernel<<<K0 / 8, 256, 0, stream>>>(x0, perm0, gate0, xp);
  edge_compact_kernel<<<512, 256, 0, stream>>>(ei, ei + E0, nullptr, E0, map0, e1s, e1d,
                                               ctrl + 0, CAP1, cur1);
  scan_kernel<<<1, 1024, 0, stream>>>(cur1, rowptr1, K0);
  scatter_kernel<<<1024, 256, 0, stream>>>(e1s, e1d, ctrl + 0, CAP1, cur1, csr1);
  agg_kernel<<<K0 / 8, 256, 0, stream>>>(xp, rowptr1, csr1, nullptr, mean, K0);
  gemm_kernel<<<K0 / 64, 256, 0, stream>>>(mean, xp, nullptr, Wl, Wr, bias, h0, 1, nullptr, Lacc);
  lsim_score_kernel<<<K0 / 4, 256, 0, stream>>>(h0, x0, x0, perm0, sc0, Lacc, score1, ss1);

  // ---------------- down level 1 ----------------
  hist_hi_kernel<<<K0 / 256, 256, 0, stream>>>(score1, K0, hhi1);
  radix_scan_kernel<<<1, 1024, 0, stream>>>(hhi1, K1, 1, kth1, rem1, 16);
  hist_lo_kernel<<<K0 / 256, 256, 0, stream>>>(score1, K0, kth1, hlo1);
  radix_scan_kernel<<<1, 1024, 0, stream>>>(hlo1, 0, 0, kth1, rem1, 0);
  tie_collect_kernel<<<K0 / 256, 256, 0, stream>>>(score1, K0, kth1, eql1, eqn1);
  tie_mark_kernel<<<1, 64, 0, stream>>>(eql1, eqn1, rem1, map1);
  build_perm_kernel<<<K0 / 1024, 256, 0, stream>>>(score1, ss1, kth1, map1, perm1, gate1,
                                                   ctrl + 5, sc1, Lacc);  // + fused L_FP0
  pool_gather_kernel<<<K1 / 8, 256, 0, stream>>>(h0, perm1, gate1, xp);
  edge_compact_kernel<<<256, 256, 0, stream>>>(e1s, e1d, ctrl + 0, CAP1, map1, e2s, e2d,
                                               ctrl + 1, CAP2, cur2);
  scan_kernel<<<1, 1024, 0, stream>>>(cur2, rowptr2, K1);
  scatter_kernel<<<512, 256, 0, stream>>>(e2s, e2d, ctrl + 1, CAP2, cur2, csr2);
  agg_kernel<<<K1 / 8, 256, 0, stream>>>(xp, rowptr2, csr2, nullptr, mean, K1);
  gemm_kernel<<<K1 / 64, 256, 0, stream>>>(mean, xp, nullptr, Wl + 16384, Wr + 16384, bias + 128,
                                           h1, 1, nullptr, Lacc);
  lsim_score_kernel<<<K1 / 4, 256, 0, stream>>>(h1, x0, h0, perm1, sc1, Lacc, score2, ss2);

  // ---------------- down level 2 ----------------
  hist_hi_kernel<<<K1 / 256, 256, 0, stream>>>(score2, K1, hhi2);
  radix_scan_kernel<<<1, 1024, 0, stream>>>(hhi2, K2, 1, kth2, rem2, 16);
  hist_lo_kernel<<<K1 / 256, 256, 0, stream>>>(score2, K1, kth2, hlo2);
  radix_scan_kernel<<<1, 1024, 0, stream>>>(hlo2, 0, 0, kth2, rem2, 0);
  tie_collect_kernel<<<K1 / 256, 256, 0, stream>>>(score2, K1, kth2, eql2, eqn2);
  tie_mark_kernel<<<1, 64, 0, stream>>>(eql2, eqn2, rem2, map2);
  build_perm_kernel<<<K1 / 1024, 256, 0, stream>>>(score2, ss2, kth2, map2, perm2, gate2,
                                                   ctrl + 6, sc2, Lacc);  // + fused L_FP1
  pool_gather_kernel<<<K2 / 8, 256, 0, stream>>>(h1, perm2, gate2, xp);
  edge_compact_kernel<<<128, 256, 0, stream>>>(e2s, e2d, ctrl + 1, CAP2, map2, e3s, e3d,
                                               ctrl + 2, CAP3, cur3);
  scan_kernel<<<1, 1024, 0, stream>>>(cur3, rowptr3, K2);
  scatter_kernel<<<256, 256, 0, stream>>>(e3s, e3d, ctrl + 2, CAP3, cur3, csr3);
  agg_kernel<<<K2 / 8, 256, 0, stream>>>(xp, rowptr3, csr3, nullptr, mean, K2);
  gemm_kernel<<<K2 / 64, 256, 0, stream>>>(mean, xp, nullptr, Wl + 2 * 16384, Wr + 2 * 16384,
                                           bias + 256, h2, 1, nullptr, Lacc);
  lsim_score_kernel<<<K2 / 4, 256, 0, stream>>>(h2, x0, h1, perm2, sc2, Lacc, nullptr, nullptr);

  // ---------------- up path: unpool is VIRTUAL (indirection via map) ----------
  agg_kernel<<<K1 / 8, 256, 0, stream>>>(h2, rowptr2, csr2, map2, mean, K1);
  gemm_kernel<<<K1 / 64, 256, 0, stream>>>(mean, h2, map2, Wl + 4 * 16384, Wr + 4 * 16384,
                                           bias + 512, xp, 1, nullptr, Lacc);
  agg_kernel<<<K0 / 8, 256, 0, stream>>>(xp, rowptr1, csr1, map1, mean, K0);
  gemm_kernel<<<K0 / 64, 256, 0, stream>>>(mean, xp, map1, Wl + 3 * 16384, Wr + 3 * 16384,
                                           bias + 384, h0, 1, nullptr, Lacc);
  agg_kernel<<<N0 / 8, 256, 0, stream>>>(h0, rowptr0, csr0, map0, mean, N0);
  gemm_kernel<<<N0 / 64, 256, 0, stream>>>(mean, h0, map0, Wl + 5 * 16384, Wr + 5 * 16384,
                                           bias + 640, out, 0, out + (size_t)N0 * C_, Lacc);
}

// Round 10
// 1211.799 us; speedup vs baseline: 1.2872x; 1.2872x over previous
//
#include <hip/hip_runtime.h>
#include <math.h>

typedef unsigned int uint;
typedef unsigned long long u64;

#define C_ 128
static const int N0 = 65536;
static const int E0 = 1048576;
static const int K0 = 32768, K1 = 16384, K2 = 8192;
static const int CAP1 = 524288, CAP2 = 262144, CAP3 = 131072;

__device__ inline float wave_reduce_sum(float v) {
#pragma unroll
  for (int w = 32; w >= 1; w >>= 1) v += __shfl_xor(v, w, 64);
  return v;
}

// per-row squared norm + score = sqrt(ss + 1e-12). One wave per row.
__global__ void score_kernel(const float* __restrict__ x, float* __restrict__ score,
                             float* __restrict__ ss) {
  int row = blockIdx.x * 4 + (threadIdx.x >> 6);
  int lane = threadIdx.x & 63;
  float2 v = ((const float2*)(x + (size_t)row * C_))[lane];
  float s = v.x * v.x + v.y * v.y;
  s = wave_reduce_sum(s);
  if (lane == 0) { ss[row] = s; score[row] = sqrtf(s + 1e-12f); }
}

// ==== grid-parallel scan / radix machinery ====
// r9 law: a single-block kernel touching 64K elements costs 60-140us (one CU
// busy, 255 idle). Decompose: grid reduce -> <=1024-element single-block step
// -> grid apply.

// block b writes bsum[b] = sum of in[b*256 .. b*256+255]. n multiple of 256.
__global__ __launch_bounds__(256) void scan_reduce_kernel(const int* __restrict__ in,
                                                          int* __restrict__ bsum, int n) {
  int tid = threadIdx.x, lane = tid & 63, wid = tid >> 6;
  int v = in[blockIdx.x * 256 + tid];
#pragma unroll
  for (int w = 32; w >= 1; w >>= 1) v += __shfl_xor(v, w, 64);
  __shared__ int p[4];
  if (lane == 0) p[wid] = v;
  __syncthreads();
  if (tid == 0) bsum[blockIdx.x] = p[0] + p[1] + p[2] + p[3];
}

// single block: exclusive-scan bsum[0..nb) in place (nb <= 1024).
__global__ __launch_bounds__(1024) void scan_sums_kernel(int* __restrict__ bsum, int nb) {
  __shared__ int part[1024];
  int tid = threadIdx.x;
  int v = (tid < nb) ? bsum[tid] : 0;
  part[tid] = v;
  __syncthreads();
  for (int d = 1; d < 1024; d <<= 1) {
    int x = part[tid];
    if (tid >= d) x += part[tid - d];
    __syncthreads();
    part[tid] = x;
    __syncthreads();
  }
  if (tid < nb) bsum[tid] = part[tid] - v;  // exclusive
}

// block b: exclusive-scan its 256 elements + bsum[b] offset; write rowptr and
// cursor; element n-1 writes rowptr[n] = grand total.
__global__ __launch_bounds__(256) void scan_apply_kernel(int* __restrict__ cursor,
                                                         const int* __restrict__ bsum,
                                                         int* __restrict__ rowptr, int n) {
  __shared__ int part[256];
  int tid = threadIdx.x;
  int i = blockIdx.x * 256 + tid;
  int v = cursor[i];
  part[tid] = v;
  __syncthreads();
  for (int d = 1; d < 256; d <<= 1) {
    int x = part[tid];
    if (tid >= d) x += part[tid - d];
    __syncthreads();
    part[tid] = x;
    __syncthreads();
  }
  int off = bsum[blockIdx.x] + part[tid] - v;
  rowptr[i] = off;
  cursor[i] = off;
  if (i == n - 1) rowptr[n] = off + v;
}

// histogram of top 16 bits of the float key (all keys positive).
__global__ void hist_hi_kernel(const float* __restrict__ score, int n,
                               int* __restrict__ hist) {
  int i = blockIdx.x * 256 + threadIdx.x;
  if (i < n) atomicAdd(&hist[((const uint*)score)[i] >> 16], 1);
}

// histogram of low 16 bits for keys matching the hi-prefix chosen so far.
__global__ void hist_lo_kernel(const float* __restrict__ score, int n,
                               const uint* __restrict__ kth_ptr, int* __restrict__ hist) {
  uint pre = *kth_ptr >> 16;
  int i = blockIdx.x * 256 + threadIdx.x;
  if (i < n) {
    uint key = ((const uint*)score)[i];
    if ((key >> 16) == pre) atomicAdd(&hist[key & 0xFFFFu], 1);
  }
}

// single block, 256 threads: pick the bucket of the kth-largest from a
// 65536-bin hist using the 256 chunk sums in bsum. Two 256-element LDS
// suffix-scans; fold bucket into *kth at `shift`; update *rem.
__global__ __launch_bounds__(256) void radix_pick_kernel(const int* __restrict__ hist,
                                                         const int* __restrict__ bsum,
                                                         int k_init, int use_init,
                                                         uint* __restrict__ kth,
                                                         int* __restrict__ rem, int shift) {
  __shared__ int part[256];
  __shared__ int s_c;
  int tid = threadIdx.x;
  // suffix scan of chunk sums: part[c] = sum_{c'>=c} bsum[c']
  part[tid] = bsum[tid];
  __syncthreads();
  for (int d = 1; d < 256; d <<= 1) {
    int add = (tid + d < 256) ? part[tid + d] : 0;
    __syncthreads();
    part[tid] += add;
    __syncthreads();
  }
  int remv = use_init ? k_init : *rem;
  if (tid == 0) {
    int c = 255;
    while (c >= 0 && part[c] < remv) --c;  // largest chunk with suffix >= rem
    s_c = c;
  }
  __syncthreads();
  int c = s_c;
  int above = (c + 1 < 256) ? part[c + 1] : 0;
  __syncthreads();
  // suffix scan of the 256 bins inside chunk c
  part[tid] = hist[c * 256 + tid];
  __syncthreads();
  for (int d = 1; d < 256; d <<= 1) {
    int add = (tid + d < 256) ? part[tid + d] : 0;
    __syncthreads();
    part[tid] += add;
    __syncthreads();
  }
  if (tid == 0) {
    int b = 255;
    while (b >= 0 && above + part[b] < remv) --b;  // largest bin with count(>=b) >= rem
    int strictly_above = above + ((b + 1 < 256) ? part[b + 1] : 0);
    *rem = remv - strictly_above;
    *kth |= ((uint)(c * 256 + b)) << shift;
  }
}

// collect indices of keys exactly equal to kth.
__global__ void tie_collect_kernel(const float* __restrict__ score, int n,
                                   const uint* __restrict__ kth_ptr,
                                   int* __restrict__ eqlist, int* __restrict__ eqn) {
  uint kth = *kth_ptr;
  int i = blockIdx.x * 256 + threadIdx.x;
  if (i < n && ((const uint*)score)[i] == kth) {
    int p = atomicAdd(eqn, 1);
    if (p < 4096) eqlist[p] = i;
  }
}

// mark the `rem` lowest-index ties with map = -2 (top_k stable tie-break).
__global__ void tie_mark_kernel(int* __restrict__ eqlist, const int* __restrict__ eqn_ptr,
                                const int* __restrict__ rem_ptr, int* __restrict__ map) {
  if (threadIdx.x != 0) return;
  int need = *rem_ptr;
  int tot = min(*eqn_ptr, 4096);
  for (int t = 0; t < need && t < tot; ++t) {
    int mi = -1, mv = 0x7FFFFFFF;
    for (int q = 0; q < tot; ++q) { int v = eqlist[q]; if (v >= 0 && v < mv) { mv = v; mi = q; } }
    if (mi < 0) break;
    map[mv] = -2;
    eqlist[mi] = -1;
  }
}

// compact selected nodes -> perm/map/gate (+ optional fused L_FP term).
// ONE counter atomic per block. Grid must satisfy grid*1024 == n.
__global__ __launch_bounds__(256) void build_perm_kernel(
    const float* __restrict__ score, const float* __restrict__ ss,
    const uint* __restrict__ kth_ptr, int* __restrict__ map, int* __restrict__ perm,
    float* __restrict__ gate, int* __restrict__ ctr, float lfp_scale,
    float* __restrict__ Lacc) {
  const int ITER = 4;
  int tid = threadIdx.x, lane = tid & 63, wid = tid >> 6;
  __shared__ int wbase[4];
  __shared__ int gbase;
  __shared__ float pl[4];
  uint kth = *kth_ptr;
  int base = blockIdx.x * (256 * ITER);
  int cnt = 0;
#pragma unroll
  for (int l = 0; l < ITER; ++l) {
    int i = base + l * 256 + tid;
    uint key = ((const uint*)score)[i];
    if ((key > kth) || (map[i] == -2)) ++cnt;
  }
#pragma unroll
  for (int w = 32; w >= 1; w >>= 1) cnt += __shfl_xor(cnt, w, 64);
  if (lane == 0) wbase[wid] = cnt;
  __syncthreads();
  if (tid == 0) {
    int s = 0;
#pragma unroll
    for (int i = 0; i < 4; ++i) { int c = wbase[i]; wbase[i] = s; s += c; }
    gbase = s ? atomicAdd(ctr, s) : 0;
  }
  __syncthreads();
  int woff = gbase + wbase[wid];
  float lfp = 0.f;
#pragma unroll
  for (int l = 0; l < ITER; ++l) {
    int i = base + l * 256 + tid;
    uint key = ((const uint*)score)[i];
    bool sel = (key > kth) || (map[i] == -2);
    u64 m = __ballot(sel);
    if (sel) {
      int j = woff + (int)__popcll(m & ((1ull << lane) - 1ull));
      perm[j] = i;
      map[i] = j;
      float t = tanhf(score[i]);
      gate[j] = t;
      if (lfp_scale != 0.f) { float om = 1.f - t; lfp += om * om * ss[i] * lfp_scale; }
    }
    woff += (int)__popcll(m);
  }
  if (lfp_scale != 0.f) {
    lfp = wave_reduce_sum(lfp);
    if (lane == 0) pl[wid] = lfp;
    __syncthreads();
    if (tid == 0) atomicAdd(Lacc, pl[0] + pl[1] + pl[2] + pl[3]);
  }
}

// xp[j] = x[perm[j]] * gate[j]   (32 threads/row, float4)
__global__ void pool_gather_kernel(const float* __restrict__ xin, const int* __restrict__ perm,
                                   const float* __restrict__ gate, float* __restrict__ xp) {
  int t = blockIdx.x * 256 + threadIdx.x;
  int j = t >> 5, q = t & 31;
  int p = perm[j];
  float g = gate[j];
  float4 v = ((const float4*)(xin + (size_t)p * C_))[q];
  v.x *= g; v.y *= g; v.z *= g; v.w *= g;
  ((float4*)(xp + (size_t)j * C_))[q] = v;
}

// filter edges whose both endpoints survive; relabel; fused degree histogram.
// ONE output-counter atomic per 2048-edge block chunk.
__global__ __launch_bounds__(256) void edge_compact_kernel(
    const int* __restrict__ src, const int* __restrict__ dst,
    const int* __restrict__ cnt_ptr, int in_cap, const int* __restrict__ map,
    int* __restrict__ osrc, int* __restrict__ odst, int* __restrict__ octr, int cap,
    int* __restrict__ deg) {
  const int ITER = 8;
  int n = cnt_ptr ? min(*cnt_ptr, in_cap) : in_cap;
  int tid = threadIdx.x, lane = tid & 63, wid = tid >> 6;
  __shared__ int wbase[4];
  __shared__ int gbase;
  long long chunk = 256 * ITER;
  for (long long base = (long long)blockIdx.x * chunk; base < n;
       base += (long long)gridDim.x * chunk) {
    int cnt = 0;
#pragma unroll
    for (int l = 0; l < ITER; ++l) {
      long long e = base + l * 256 + tid;
      if (e < n) {
        int a = map[src[e]];
        int b = map[dst[e]];
        if (a >= 0 && b >= 0) ++cnt;
      }
    }
#pragma unroll
    for (int w = 32; w >= 1; w >>= 1) cnt += __shfl_xor(cnt, w, 64);
    __syncthreads();
    if (lane == 0) wbase[wid] = cnt;
    __syncthreads();
    if (tid == 0) {
      int s = 0;
#pragma unroll
      for (int i = 0; i < 4; ++i) { int c = wbase[i]; wbase[i] = s; s += c; }
      gbase = s ? atomicAdd(octr, s) : 0;
    }
    __syncthreads();
    int woff = gbase + wbase[wid];
#pragma unroll
    for (int l = 0; l < ITER; ++l) {
      long long e = base + l * 256 + tid;
      int a = -1, b = -1;
      bool keep = false;
      if (e < n) {
        a = map[src[e]];
        b = map[dst[e]];
        keep = (a >= 0 && b >= 0);
      }
      u64 m = __ballot(keep);
      if (keep) {
        int p = woff + (int)__popcll(m & ((1ull << lane) - 1ull));
        if (p < cap) {
          osrc[p] = a;
          odst[p] = b;
          atomicAdd(&deg[b], 1);
        }
      }
      woff += (int)__popcll(m);
    }
  }
}

__global__ void hist_kernel(const int* __restrict__ dst, int n, int* __restrict__ deg) {
  for (int e = blockIdx.x * 256 + threadIdx.x; e < n; e += gridDim.x * 256)
    atomicAdd(&deg[dst[e]], 1);
}

__global__ void scatter_kernel(const int* __restrict__ src, const int* __restrict__ dst,
                               const int* __restrict__ cnt_ptr, int cap,
                               int* __restrict__ cursor, int* __restrict__ csr) {
  int n = cnt_ptr ? min(*cnt_ptr, cap) : cap;
  for (int e = blockIdx.x * 256 + threadIdx.x; e < n; e += gridDim.x * 256) {
    int p = atomicAdd(&cursor[dst[e]], 1);
    csr[p] = src[e];
  }
}

// mean[node] = (sum over CSR row) / max(deg,1). 32 threads/node, float4.
// fmap mode: x row = x[fmap[s]] if selected, else 0 (virtual unpool).
__global__ void agg_kernel(const float* __restrict__ x, const int* __restrict__ rowptr,
                           const int* __restrict__ csr, const int* __restrict__ fmap,
                           float* __restrict__ mean, int n) {
  int t = blockIdx.x * 256 + threadIdx.x;
  int node = t >> 5, q = t & 31;
  if (node >= n) return;
  int beg = rowptr[node], end = rowptr[node + 1];
  float4 acc = make_float4(0.f, 0.f, 0.f, 0.f);
  if (fmap) {
    for (int p = beg; p < end; ++p) {
      int m = fmap[csr[p]];
      if (m < 0) continue;
      float4 v = ((const float4*)(x + (size_t)m * C_))[q];
      acc.x += v.x; acc.y += v.y; acc.z += v.z; acc.w += v.w;
    }
  } else {
    for (int p = beg; p < end; ++p) {
      int s = csr[p];
      float4 v = ((const float4*)(x + (size_t)s * C_))[q];
      acc.x += v.x; acc.y += v.y; acc.z += v.z; acc.w += v.w;
    }
  }
  float inv = 1.f / fmaxf((float)(end - beg), 1.f);
  acc.x *= inv; acc.y *= inv; acc.z *= inv; acc.w *= inv;
  ((float4*)(mean + (size_t)node * C_))[q] = acc;
}

// out[row] = mean[row] @ Wl + Xsrc[xrow] @ Wr + b (optional relu).
__global__ __launch_bounds__(256) void gemm_kernel(const float* __restrict__ Amean,
                                                   const float* __restrict__ Xsrc,
                                                   const int* __restrict__ xmask,
                                                   const float* __restrict__ Wl,
                                                   const float* __restrict__ Wr,
                                                   const float* __restrict__ bias,
                                                   float* __restrict__ out, int relu,
                                                   float* __restrict__ Lout,
                                                   const float* __restrict__ Lacc) {
  __shared__ alignas(16) float As[32][68];
  __shared__ alignas(16) float Ws[32][128];
  __shared__ int rm[64];
  int tid = threadIdx.x;
  int row0 = blockIdx.x * 64;
  if (tid < 64) rm[tid] = xmask ? xmask[row0 + tid] : (row0 + tid);
  if (Lout && blockIdx.x == 0 && tid == 0) Lout[0] = *Lacc;
  int trow = tid >> 4;
  int tcol = tid & 15;
  float acc[4][8];
#pragma unroll
  for (int i = 0; i < 4; ++i)
#pragma unroll
    for (int j = 0; j < 8; ++j) acc[i][j] = 0.f;
  __syncthreads();
  for (int phase = 0; phase < 2; ++phase) {
    const float* A = phase ? Xsrc : Amean;
    const float* W = phase ? Wr : Wl;
    for (int kc = 0; kc < 128; kc += 32) {
#pragma unroll
      for (int l = 0; l < 2; ++l) {
        int f = tid + l * 256;
        int r = f >> 3, c4 = (f & 7) << 2;
        int xr = phase ? rm[r] : (row0 + r);
        float4 v = make_float4(0.f, 0.f, 0.f, 0.f);
        if (xr >= 0) v = *(const float4*)(A + (size_t)xr * C_ + kc + c4);
        As[c4 + 0][r] = v.x; As[c4 + 1][r] = v.y; As[c4 + 2][r] = v.z; As[c4 + 3][r] = v.w;
      }
#pragma unroll
      for (int l = 0; l < 4; ++l) {
        int f = tid + l * 256;
        int kk = f >> 5, c4 = (f & 31) << 2;
        *(float4*)(&Ws[kk][c4]) = *(const float4*)(W + (size_t)(kc + kk) * C_ + c4);
      }
      __syncthreads();
#pragma unroll
      for (int kk = 0; kk < 32; ++kk) {
        float a[4], w[8];
#pragma unroll
        for (int i = 0; i < 4; ++i) a[i] = As[kk][trow * 4 + i];
#pragma unroll
        for (int j = 0; j < 8; ++j) w[j] = Ws[kk][tcol * 8 + j];
#pragma unroll
        for (int i = 0; i < 4; ++i)
#pragma unroll
          for (int j = 0; j < 8; ++j) acc[i][j] = fmaf(a[i], w[j], acc[i][j]);
      }
      __syncthreads();
    }
  }
#pragma unroll
  for (int i = 0; i < 4; ++i) {
    int r = row0 + trow * 4 + i;
#pragma unroll
    for (int j = 0; j < 8; ++j) {
      float v = acc[i][j] + bias[tcol * 8 + j];
      if (relu) v = fmaxf(v, 0.f);
      out[(size_t)r * C_ + tcol * 8 + j] = v;
    }
  }
}

// fused: L_similarity + L_regularization + next level's score/ss.
__global__ void lsim_score_kernel(const float* __restrict__ h, const float* __restrict__ x0,
                                  const float* __restrict__ xin, const int* __restrict__ perm,
                                  float scale, float* __restrict__ Lacc,
                                  float* __restrict__ score, float* __restrict__ ss) {
  int row = blockIdx.x * 4 + (threadIdx.x >> 6);
  int lane = threadIdx.x & 63;
  int p = perm[row];
  float2 hv = ((const float2*)(h + (size_t)row * C_))[lane];
  float2 a = ((const float2*)(x0 + (size_t)p * C_))[lane];
  float2 bv = (xin == x0) ? a : ((const float2*)(xin + (size_t)p * C_))[lane];
  float d1x = hv.x - a.x, d1y = hv.y - a.y;
  float l = d1x * d1x + d1y * d1y + fabsf(hv.x - bv.x) + fabsf(hv.y - bv.y);
  float s2 = hv.x * hv.x + hv.y * hv.y;
#pragma unroll
  for (int w = 32; w >= 1; w >>= 1) { l += __shfl_xor(l, w, 64); s2 += __shfl_xor(s2, w, 64); }
  __shared__ float pl[4];
  int wid = threadIdx.x >> 6;
  if (lane == 0) {
    pl[wid] = l;
    if (score) { ss[row] = s2; score[row] = sqrtf(s2 + 1e-12f); }
  }
  __syncthreads();
  if (threadIdx.x == 0) atomicAdd(Lacc, (pl[0] + pl[1] + pl[2] + pl[3]) * scale);
}

extern "C" void kernel_launch(void* const* d_in, const int* in_sizes, int n_in, void* d_out,
                              int out_size, void* d_ws, size_t ws_size, hipStream_t stream) {
  const float* x0 = (const float*)d_in[0];
  const int* ei = (const int*)d_in[1];
  const float* Wl = (const float*)d_in[2];
  const float* Wr = (const float*)d_in[3];
  const float* bias = (const float*)d_in[4];
  float* out = (float*)d_out;

  char* base = (char*)d_ws;
  size_t off = 0;
  auto alloc = [&](size_t bytes) -> char* {
    char* p = base + off;
    off = (off + bytes + 255) & ~(size_t)255;
    return p;
  };

  // ---- zeroed region (one memset) ----
  int* ctrl = (int*)alloc(1024 * 4);
  // ctrl ints: 0..2 edge ctr, 4..6 perm ctr, 8..10 kth, 12..14 rem,
  //            16 Lacc(float), 20..22 eqn
  int* cur0 = (int*)alloc((size_t)(N0 + 1) * 4);
  int* cur1 = (int*)alloc((size_t)(K0 + 1) * 4);
  int* cur2 = (int*)alloc((size_t)(K1 + 1) * 4);
  int* cur3 = (int*)alloc((size_t)(K2 + 1) * 4);
  int* hhi0 = (int*)alloc(65536 * 4);
  int* hlo0 = (int*)alloc(65536 * 4);
  int* hhi1 = (int*)alloc(65536 * 4);
  int* hlo1 = (int*)alloc(65536 * 4);
  int* hhi2 = (int*)alloc(65536 * 4);
  int* hlo2 = (int*)alloc(65536 * 4);
  size_t zero_bytes = (size_t)((base + off) - (char*)ctrl);
  // ---- 0xFF region (one memset) ----
  int* map0 = (int*)alloc((size_t)N0 * 4);
  int* map1 = (int*)alloc((size_t)K0 * 4);
  int* map2 = (int*)alloc((size_t)K1 * 4);
  size_t ff_bytes = (size_t)((base + off) - (char*)map0);
  // ---- uninitialized (fully written before read every call) ----
  int* bsum = (int*)alloc(1024 * 4);  // shared scratch: block sums (stream-ordered reuse)
  int* eql0 = (int*)alloc(4096 * 4);
  int* eql1 = (int*)alloc(4096 * 4);
  int* eql2 = (int*)alloc(4096 * 4);
  float* score0 = (float*)alloc((size_t)N0 * 4);
  float* ss0 = (float*)alloc((size_t)N0 * 4);
  float* score1 = (float*)alloc((size_t)K0 * 4);
  float* ss1 = (float*)alloc((size_t)K0 * 4);
  float* score2 = (float*)alloc((size_t)K1 * 4);
  float* ss2 = (float*)alloc((size_t)K1 * 4);
  int* perm0 = (int*)alloc((size_t)K0 * 4);
  int* perm1 = (int*)alloc((size_t)K1 * 4);
  int* perm2 = (int*)alloc((size_t)K2 * 4);
  float* gate0 = (float*)alloc((size_t)K0 * 4);
  float* gate1 = (float*)alloc((size_t)K1 * 4);
  float* gate2 = (float*)alloc((size_t)K2 * 4);
  int* e1s = (int*)alloc((size_t)CAP1 * 4);
  int* e1d = (int*)alloc((size_t)CAP1 * 4);
  int* e2s = (int*)alloc((size_t)CAP2 * 4);
  int* e2d = (int*)alloc((size_t)CAP2 * 4);
  int* e3s = (int*)alloc((size_t)CAP3 * 4);
  int* e3d = (int*)alloc((size_t)CAP3 * 4);
  int* rowptr0 = (int*)alloc((size_t)(N0 + 1) * 4);
  int* rowptr1 = (int*)alloc((size_t)(K0 + 1) * 4);
  int* rowptr2 = (int*)alloc((size_t)(K1 + 1) * 4);
  int* rowptr3 = (int*)alloc((size_t)(K2 + 1) * 4);
  int* csr0 = (int*)alloc((size_t)E0 * 4);
  int* csr1 = (int*)alloc((size_t)CAP1 * 4);
  int* csr2 = (int*)alloc((size_t)CAP2 * 4);
  int* csr3 = (int*)alloc((size_t)CAP3 * 4);
  float* xp = (float*)alloc((size_t)K0 * C_ * 4);  // pooled input / hup2
  float* h0 = (float*)alloc((size_t)K0 * C_ * 4);  // down h0, later hup1
  float* h1 = (float*)alloc((size_t)K1 * C_ * 4);
  float* h2 = (float*)alloc((size_t)K2 * C_ * 4);
  float* mean = (float*)alloc((size_t)N0 * C_ * 4);

  uint* kth0 = (uint*)(ctrl + 8);
  uint* kth1 = (uint*)(ctrl + 9);
  uint* kth2 = (uint*)(ctrl + 10);
  int* rem0 = ctrl + 12;
  int* rem1 = ctrl + 13;
  int* rem2 = ctrl + 14;
  float* Lacc = (float*)(ctrl + 16);
  int* eqn0 = ctrl + 20;
  int* eqn1 = ctrl + 21;
  int* eqn2 = ctrl + 22;
  const float sc0 = 1.f / ((float)K0 * C_);
  const float sc1 = 1.f / ((float)K1 * C_);
  const float sc2 = 1.f / ((float)K2 * C_);

  hipMemsetAsync(ctrl, 0, zero_bytes, stream);
  hipMemsetAsync(map0, 0xFF, ff_bytes, stream);

  // CSR over original edges (for the final conv)
  hist_kernel<<<2048, 256, 0, stream>>>(ei + E0, E0, cur0);
  scan_reduce_kernel<<<N0 / 256, 256, 0, stream>>>(cur0, bsum, N0);
  scan_sums_kernel<<<1, 1024, 0, stream>>>(bsum, N0 / 256);
  scan_apply_kernel<<<N0 / 256, 256, 0, stream>>>(cur0, bsum, rowptr0, N0);
  scatter_kernel<<<2048, 256, 0, stream>>>(ei, ei + E0, nullptr, E0, cur0, csr0);

  // ---------------- down level 0 ----------------
  score_kernel<<<N0 / 4, 256, 0, stream>>>(x0, score0, ss0);
  hist_hi_kernel<<<N0 / 256, 256, 0, stream>>>(score0, N0, hhi0);
  scan_reduce_kernel<<<256, 256, 0, stream>>>(hhi0, bsum, 65536);
  radix_pick_kernel<<<1, 256, 0, stream>>>(hhi0, bsum, K0, 1, kth0, rem0, 16);
  hist_lo_kernel<<<N0 / 256, 256, 0, stream>>>(score0, N0, kth0, hlo0);
  scan_reduce_kernel<<<256, 256, 0, stream>>>(hlo0, bsum, 65536);
  radix_pick_kernel<<<1, 256, 0, stream>>>(hlo0, bsum, 0, 0, kth0, rem0, 0);
  tie_collect_kernel<<<N0 / 256, 256, 0, stream>>>(score0, N0, kth0, eql0, eqn0);
  tie_mark_kernel<<<1, 64, 0, stream>>>(eql0, eqn0, rem0, map0);
  build_perm_kernel<<<N0 / 1024, 256, 0, stream>>>(score0, ss0, kth0, map0, perm0, gate0,
                                                   ctrl + 4, 0.f, Lacc);
  pool_gather_kernel<<<K0 / 8, 256, 0, stream>>>(x0, perm0, gate0, xp);
  edge_compact_kernel<<<512, 256, 0, stream>>>(ei, ei + E0, nullptr, E0, map0, e1s, e1d,
                                               ctrl + 0, CAP1, cur1);
  scan_reduce_kernel<<<K0 / 256, 256, 0, stream>>>(cur1, bsum, K0);
  scan_sums_kernel<<<1, 1024, 0, stream>>>(bsum, K0 / 256);
  scan_apply_kernel<<<K0 / 256, 256, 0, stream>>>(cur1, bsum, rowptr1, K0);
  scatter_kernel<<<1024, 256, 0, stream>>>(e1s, e1d, ctrl + 0, CAP1, cur1, csr1);
  agg_kernel<<<K0 / 8, 256, 0, stream>>>(xp, rowptr1, csr1, nullptr, mean, K0);
  gemm_kernel<<<K0 / 64, 256, 0, stream>>>(mean, xp, nullptr, Wl, Wr, bias, h0, 1, nullptr, Lacc);
  lsim_score_kernel<<<K0 / 4, 256, 0, stream>>>(h0, x0, x0, perm0, sc0, Lacc, score1, ss1);

  // ---------------- down level 1 ----------------
  hist_hi_kernel<<<K0 / 256, 256, 0, stream>>>(score1, K0, hhi1);
  scan_reduce_kernel<<<256, 256, 0, stream>>>(hhi1, bsum, 65536);
  radix_pick_kernel<<<1, 256, 0, stream>>>(hhi1, bsum, K1, 1, kth1, rem1, 16);
  hist_lo_kernel<<<K0 / 256, 256, 0, stream>>>(score1, K0, kth1, hlo1);
  scan_reduce_kernel<<<256, 256, 0, stream>>>(hlo1, bsum, 65536);
  radix_pick_kernel<<<1, 256, 0, stream>>>(hlo1, bsum, 0, 0, kth1, rem1, 0);
  tie_collect_kernel<<<K0 / 256, 256, 0, stream>>>(score1, K0, kth1, eql1, eqn1);
  tie_mark_kernel<<<1, 64, 0, stream>>>(eql1, eqn1, rem1, map1);
  build_perm_kernel<<<K0 / 1024, 256, 0, stream>>>(score1, ss1, kth1, map1, perm1, gate1,
                                                   ctrl + 5, sc1, Lacc);  // + fused L_FP0
  pool_gather_kernel<<<K1 / 8, 256, 0, stream>>>(h0, perm1, gate1, xp);
  edge_compact_kernel<<<256, 256, 0, stream>>>(e1s, e1d, ctrl + 0, CAP1, map1, e2s, e2d,
                                               ctrl + 1, CAP2, cur2);
  scan_reduce_kernel<<<K1 / 256, 256, 0, stream>>>(cur2, bsum, K1);
  scan_sums_kernel<<<1, 1024, 0, stream>>>(bsum, K1 / 256);
  scan_apply_kernel<<<K1 / 256, 256, 0, stream>>>(cur2, bsum, rowptr2, K1);
  scatter_kernel<<<512, 256, 0, stream>>>(e2s, e2d, ctrl + 1, CAP2, cur2, csr2);
  agg_kernel<<<K1 / 8, 256, 0, stream>>>(xp, rowptr2, csr2, nullptr, mean, K1);
  gemm_kernel<<<K1 / 64, 256, 0, stream>>>(mean, xp, nullptr, Wl + 16384, Wr + 16384, bias + 128,
                                           h1, 1, nullptr, Lacc);
  lsim_score_kernel<<<K1 / 4, 256, 0, stream>>>(h1, x0, h0, perm1, sc1, Lacc, score2, ss2);

  // ---------------- down level 2 ----------------
  hist_hi_kernel<<<K1 / 256, 256, 0, stream>>>(score2, K1, hhi2);
  scan_reduce_kernel<<<256, 256, 0, stream>>>(hhi2, bsum, 65536);
  radix_pick_kernel<<<1, 256, 0, stream>>>(hhi2, bsum, K2, 1, kth2, rem2, 16);
  hist_lo_kernel<<<K1 / 256, 256, 0, stream>>>(score2, K1, kth2, hlo2);
  scan_reduce_kernel<<<256, 256, 0, stream>>>(hlo2, bsum, 65536);
  radix_pick_kernel<<<1, 256, 0, stream>>>(hlo2, bsum, 0, 0, kth2, rem2, 0);
  tie_collect_kernel<<<K1 / 256, 256, 0, stream>>>(score2, K1, kth2, eql2, eqn2);
  tie_mark_kernel<<<1, 64, 0, stream>>>(eql2, eqn2, rem2, map2);
  build_perm_kernel<<<K1 / 1024, 256, 0, stream>>>(score2, ss2, kth2, map2, perm2, gate2,
                                                   ctrl + 6, sc2, Lacc);  // + fused L_FP1
  pool_gather_kernel<<<K2 / 8, 256, 0, stream>>>(h1, perm2, gate2, xp);
  edge_compact_kernel<<<128, 256, 0, stream>>>(e2s, e2d, ctrl + 1, CAP2, map2, e3s, e3d,
                                               ctrl + 2, CAP3, cur3);
  scan_reduce_kernel<<<K2 / 256, 256, 0, stream>>>(cur3, bsum, K2);
  scan_sums_kernel<<<1, 1024, 0, stream>>>(bsum, K2 / 256);
  scan_apply_kernel<<<K2 / 256, 256, 0, stream>>>(cur3, bsum, rowptr3, K2);
  scatter_kernel<<<256, 256, 0, stream>>>(e3s, e3d, ctrl + 2, CAP3, cur3, csr3);
  agg_kernel<<<K2 / 8, 256, 0, stream>>>(xp, rowptr3, csr3, nullptr, mean, K2);
  gemm_kernel<<<K2 / 64, 256, 0, stream>>>(mean, xp, nullptr, Wl + 2 * 16384, Wr + 2 * 16384,
                                           bias + 256, h2, 1, nullptr, Lacc);
  lsim_score_kernel<<<K2 / 4, 256, 0, stream>>>(h2, x0, h1, perm2, sc2, Lacc, nullptr, nullptr);

  // ---------------- up path: unpool is VIRTUAL (indirection via map) ----------
  agg_kernel<<<K1 / 8, 256, 0, stream>>>(h2, rowptr2, csr2, map2, mean, K1);
  gemm_kernel<<<K1 / 64, 256, 0, stream>>>(mean, h2, map2, Wl + 4 * 16384, Wr + 4 * 16384,
                                           bias + 512, xp, 1, nullptr, Lacc);
  agg_kernel<<<K0 / 8, 256, 0, stream>>>(xp, rowptr1, csr1, map1, mean, K0);
  gemm_kernel<<<K0 / 64, 256, 0, stream>>>(mean, xp, map1, Wl + 3 * 16384, Wr + 3 * 16384,
                                           bias + 384, h0, 1, nullptr, Lacc);
  agg_kernel<<<N0 / 8, 256, 0, stream>>>(h0, rowptr0, csr0, map0, mean, N0);
  gemm_kernel<<<N0 / 64, 256, 0, stream>>>(mean, h0, map0, Wl + 5 * 16384, Wr + 5 * 16384,
                                           bias + 640, out, 0, out + (size_t)N0 * C_, Lacc);
}